// Round 1
// baseline (2969.380 us; speedup 1.0000x reference)
//
#include <hip/hip_runtime.h>
#include <stdint.h>

// ---------------------------------------------------------------------------
// BesselConv2d on MI355X (gfx950)
//
// reference = conv(x, Wf) with Wf = complex T@w filter bank (2048 out ch),
// then sum over (2, M) groups of squared responses + bias.
//
// Implementation:
//  k1: pad+convert x (fp32 NCHW) -> xp bf16 NHWC, zero-padded to 72x72.
//      NHWC => conv A-tile for any tap = contiguous [64 pix][64 cin] block.
//  k2: build Wfb[tap][ch'][cin] bf16 where ch' = cout*32 + (part*16+m).
//      Channel reorder puts all 32 reduction groups of a cout into one
//      128-wide channel tile -> block-local reduction, no atomics.
//  k3: implicit-GEMM conv, m97 structure: 128x128 tile, 4 waves,
//      global_load_lds(16B) staging, 16x16x32 bf16 MFMA, fused
//      square->shuffle-reduce->bias epilogue.
// ---------------------------------------------------------------------------

typedef unsigned short ushort_t;
typedef __attribute__((ext_vector_type(8))) short short8;   // 8 bf16 = 4 VGPRs
typedef __attribute__((ext_vector_type(4))) float float4v;  // 4 fp32 acc

typedef const void __attribute__((address_space(1)))* gptr_t;
typedef void __attribute__((address_space(3)))* sptr_t;

__device__ __forceinline__ ushort_t f2bf(float f) {
    union { float f; uint32_t u; } v; v.f = f;
    uint32_t u = v.u;
    u += 0x7fffu + ((u >> 16) & 1u);   // round-to-nearest-even
    return (ushort_t)(u >> 16);
}

// ---------------------------------------------------------------------------
// Kernel 1: x[32][64][64][64] (NCHW fp32) -> xp[32][72][72][64] (NHWC bf16, 0-pad 4)
// block = (h', b); LDS transpose (65-pad) for coalesced read AND write.
// ---------------------------------------------------------------------------
__global__ __launch_bounds__(256) void pad_kernel(const float* __restrict__ x,
                                                  ushort_t* __restrict__ xp) {
    __shared__ float lds[64 * 65];
    const int hp  = blockIdx.x;   // 0..71
    const int b   = blockIdx.y;   // 0..31
    const int tid = threadIdx.x;
    const int h   = hp - 4;
    const bool hvalid = (h >= 0 && h < 64);
    if (hvalid) {
        #pragma unroll
        for (int it = 0; it < 16; ++it) {
            int idx = it * 256 + tid;
            int cin = idx >> 6, w = idx & 63;           // w fastest -> coalesced
            lds[w * 65 + cin] = x[((b * 64 + cin) * 64 + h) * 64 + w];
        }
    }
    __syncthreads();
    #pragma unroll
    for (int it = 0; it < 18; ++it) {
        int o = it * 256 + tid;                         // 72*64 = 4608 elems
        int wp = o >> 6, cin = o & 63;                  // cin fastest -> coalesced
        int w = wp - 4;
        float val = (hvalid && w >= 0 && w < 64) ? lds[w * 65 + cin] : 0.0f;
        xp[((b * 72 + hp) * 72 + wp) * 64 + cin] = f2bf(val);
    }
}

// ---------------------------------------------------------------------------
// Kernel 2: Wfb[t][ch'][cin] bf16, ch' = cout*32 + g, g = part*16 + m.
//   part 0: sum_j Tr*wr - Ti*wi ; part 1: sum_j Tr*wi + Ti*wr
// block = (g, t); coalesced w reads (cc fastest), LDS transpose, coalesced writes.
// ---------------------------------------------------------------------------
__global__ __launch_bounds__(256) void wf_kernel(const float* __restrict__ Tr,
                                                 const float* __restrict__ Ti,
                                                 const float* __restrict__ wr,
                                                 const float* __restrict__ wi,
                                                 ushort_t* __restrict__ Wfb) {
    __shared__ float lds[64 * 65];
    const int g   = blockIdx.x;        // 0..31 = part*16 + m
    const int t   = blockIdx.y;        // 0..80
    const int part = g >> 4, m = g & 15;
    const int tid = threadIdx.x;
    #pragma unroll
    for (int it = 0; it < 16; ++it) {
        int cc = it * 256 + tid;       // cc = cin*64 + cout, consecutive -> coalesced
        float acc = 0.f;
        #pragma unroll
        for (int j = 0; j < 8; ++j) {
            float tr  = Tr[(m * 81 + t) * 8 + j];       // wave-uniform (scalar)
            float ti  = Ti[(m * 81 + t) * 8 + j];
            float wrv = wr[(m * 8 + j) * 4096 + cc];
            float wiv = wi[(m * 8 + j) * 4096 + cc];
            acc += (part == 0) ? (tr * wrv - ti * wiv) : (tr * wiv + ti * wrv);
        }
        lds[(cc & 63) * 65 + (cc >> 6)] = acc;          // lds[cout][cin], stride-65
    }
    __syncthreads();
    #pragma unroll
    for (int it = 0; it < 16; ++it) {
        int o = it * 256 + tid;        // o = cout*64 + cin
        int cout = o >> 6, cin = o & 63;
        Wfb[(t * 2048 + cout * 32 + g) * 64 + cin] = f2bf(lds[cout * 65 + cin]);
    }
}

// ---------------------------------------------------------------------------
// Kernel 3: implicit-GEMM conv + fused square/group-reduce/bias epilogue.
// Block tile: 128 pixels (2 rows of 64) x 128 channels; 4 waves, wave = 64x64.
// K-loop: 81 taps x (cin=64 -> 2x MFMA 16x16x32 bf16 K-steps).
// A tile As[128][64]: contiguous in global per row-> global_load_lds 16B chunks.
// B tile Bs[128][64]: Wfb slice, one contiguous 16 KB block per tap.
// ---------------------------------------------------------------------------
__global__ __launch_bounds__(256, 3) void conv_kernel(const ushort_t* __restrict__ xp,
                                                      const ushort_t* __restrict__ Wfb,
                                                      const float* __restrict__ bias,
                                                      float* __restrict__ out) {
    __shared__ ushort_t As[128 * 64];   // [pixel][cin] 16 KB
    __shared__ ushort_t Bs[128 * 64];   // [ch'][cin]   16 KB

    const int pt  = blockIdx.x;         // 0..1023 pixel tile (fast-varying -> B slice L2-hot)
    const int ct  = blockIdx.y;         // 0..15 channel tile
    const int b   = pt >> 5;
    const int h0  = (pt & 31) * 2;      // rows h0, h0+1
    const int tid = threadIdx.x;
    const int wv  = tid >> 6;
    const int lane = tid & 63;
    const int wrow = wv >> 1, wcol = wv & 1;   // wave quadrant: pixels / channels
    const int quad = lane >> 4, lr = lane & 15;

    float4v acc[4][4];
    #pragma unroll
    for (int i = 0; i < 4; ++i)
        #pragma unroll
        for (int j = 0; j < 4; ++j) {
            float4v z = {0.f, 0.f, 0.f, 0.f};
            acc[i][j] = z;
        }

    const char* xpb = (const char*)xp;
    const char* wfb = (const char*)Wfb;
    const size_t bbase = (size_t)((0 * 2048 + ct * 128) * 64) * 2;  // + t*2048*64*2 per tap

    for (int dy = 0; dy < 9; ++dy) {
        for (int dx = 0; dx < 9; ++dx) {
            const int t = dy * 9 + dx;
            __syncthreads();   // previous iter's readers done before overwrite
            if (wv < 2) {
                // waves 0,1: A chunks 0..15 (1 KB each: 8 pixels x 64 cin)
                #pragma unroll
                for (int k = 0; k < 8; ++k) {
                    const int c = wv * 8 + k;
                    const int r = c >> 3;                  // pixel row 0/1
                    const char* g = xpb
                        + (size_t)(((b * 72 + h0 + r + dy) * 72 + dx) * 64) * 2
                        + (size_t)(c & 7) * 1024 + (size_t)lane * 16;
                    __builtin_amdgcn_global_load_lds((gptr_t)g,
                        (sptr_t)((char*)As + c * 1024), 16, 0, 0);
                }
            } else {
                // waves 2,3: B chunks 0..15
                #pragma unroll
                for (int k = 0; k < 8; ++k) {
                    const int c2 = (wv - 2) * 8 + k;
                    const char* g = wfb + bbase
                        + (size_t)t * (2048 * 64 * 2)
                        + (size_t)c2 * 1024 + (size_t)lane * 16;
                    __builtin_amdgcn_global_load_lds((gptr_t)g,
                        (sptr_t)((char*)Bs + c2 * 1024), 16, 0, 0);
                }
            }
            __syncthreads();   // compiler drains vmcnt before barrier (m97 structure)

            #pragma unroll
            for (int kk = 0; kk < 2; ++kk) {
                short8 a[4], bb[4];
                #pragma unroll
                for (int i = 0; i < 4; ++i)
                    a[i] = *(const short8*)&As[(wrow * 64 + i * 16 + lr) * 64 + kk * 32 + quad * 8];
                #pragma unroll
                for (int j = 0; j < 4; ++j)
                    bb[j] = *(const short8*)&Bs[(wcol * 64 + j * 16 + lr) * 64 + kk * 32 + quad * 8];
                #pragma unroll
                for (int i = 0; i < 4; ++i)
                    #pragma unroll
                    for (int j = 0; j < 4; ++j)
                        acc[i][j] = __builtin_amdgcn_mfma_f32_16x16x32_bf16(
                            a[i], bb[j], acc[i][j], 0, 0, 0);
            }
        }
    }

    // Epilogue: wave's 64 channels = 2 couts x 32 groups (ch' = cout*32+g).
    // j=0: cout0,g=lr ; j=1: cout0,g=16+lr ; j=2: cout1,g=lr ; j=3: cout1,g=16+lr.
    // Square, pair-sum, butterfly over the 16-lane group -> full 32-group sum.
    const int c0 = ct * 4 + wcol * 2;
    const float b0 = bias[c0], b1 = bias[c0 + 1];
    #pragma unroll
    for (int i = 0; i < 4; ++i) {
        #pragma unroll
        for (int reg = 0; reg < 4; ++reg) {
            float v0 = acc[i][0][reg] * acc[i][0][reg] + acc[i][1][reg] * acc[i][1][reg];
            float v1 = acc[i][2][reg] * acc[i][2][reg] + acc[i][3][reg] * acc[i][3][reg];
            #pragma unroll
            for (int off = 1; off <= 8; off <<= 1) {
                v0 += __shfl_xor(v0, off, 64);
                v1 += __shfl_xor(v1, off, 64);
            }
            if (lr == 0) {
                const int p = wrow * 64 + i * 16 + quad * 4 + reg;
                const int h = h0 + (p >> 6), w = p & 63;
                out[((b * 64 + c0    ) * 64 + h) * 64 + w] = v0 + b0;
                out[((b * 64 + c0 + 1) * 64 + h) * 64 + w] = v1 + b1;
            }
        }
    }
}

// ---------------------------------------------------------------------------
extern "C" void kernel_launch(void* const* d_in, const int* in_sizes, int n_in,
                              void* d_out, int out_size, void* d_ws, size_t ws_size,
                              hipStream_t stream) {
    const float* x    = (const float*)d_in[0];
    const float* Tr   = (const float*)d_in[1];
    const float* Ti   = (const float*)d_in[2];
    const float* wr   = (const float*)d_in[3];
    const float* wi   = (const float*)d_in[4];
    const float* bias = (const float*)d_in[5];
    float* out = (float*)d_out;

    // workspace: xp = 32*72*72*64 bf16 = 21,233,664 B ; Wfb = 81*2048*64 bf16 = same
    ushort_t* xp  = (ushort_t*)d_ws;
    ushort_t* Wfb = (ushort_t*)((char*)d_ws + 21233664);

    pad_kernel<<<dim3(72, 32), 256, 0, stream>>>(x, xp);
    wf_kernel<<<dim3(32, 81), 256, 0, stream>>>(Tr, Ti, wr, wi, Wfb);
    conv_kernel<<<dim3(1024, 16), 256, 0, stream>>>(xp, Wfb, bias, out);
}

// Round 2
// 2687.992 us; speedup vs baseline: 1.1047x; 1.1047x over previous
//
#include <hip/hip_runtime.h>
#include <stdint.h>

// ---------------------------------------------------------------------------
// BesselConv2d on MI355X (gfx950)
//
// reference = conv(x, Wf) with Wf = complex T@w filter bank (2048 out ch),
// then sum over (2, M) groups of squared responses + bias.
//
// Implementation:
//  k1: pad+convert x (fp32 NCHW) -> xp bf16 NHWC, zero-padded to 72x72.
//  k2: build Wfb[tap][ch'][cin] bf16 where ch' = cout*32 + (part*16+m).
//  k3: implicit-GEMM conv, m97 structure: 128x128 tile, 4 waves,
//      global_load_lds(16B) staging, 16x16x32 bf16 MFMA, fused
//      square->shuffle-reduce->bias epilogue.
//
// R2 change: XOR 16B-segment swizzle on As/Bs to kill the 16-way LDS bank
// conflicts on fragment ds_read_b128 (R1: SQ_LDS_BANK_CONFLICT=1.02e9,
// ~47% of conv cycles). Write-side swizzle is applied by permuting the
// global source lane offsets (LDS side of global_load_lds is fixed to
// base+lane*16); read-side applies seg^= (row&7).
// ---------------------------------------------------------------------------

typedef unsigned short ushort_t;
typedef __attribute__((ext_vector_type(8))) short short8;   // 8 bf16 = 4 VGPRs
typedef __attribute__((ext_vector_type(4))) float float4v;  // 4 fp32 acc

typedef const void __attribute__((address_space(1)))* gptr_t;
typedef void __attribute__((address_space(3)))* sptr_t;

__device__ __forceinline__ ushort_t f2bf(float f) {
    union { float f; uint32_t u; } v; v.f = f;
    uint32_t u = v.u;
    u += 0x7fffu + ((u >> 16) & 1u);   // round-to-nearest-even
    return (ushort_t)(u >> 16);
}

// ---------------------------------------------------------------------------
// Kernel 1: x[32][64][64][64] (NCHW fp32) -> xp[32][72][72][64] (NHWC bf16, 0-pad 4)
// ---------------------------------------------------------------------------
__global__ __launch_bounds__(256) void pad_kernel(const float* __restrict__ x,
                                                  ushort_t* __restrict__ xp) {
    __shared__ float lds[64 * 65];
    const int hp  = blockIdx.x;   // 0..71
    const int b   = blockIdx.y;   // 0..31
    const int tid = threadIdx.x;
    const int h   = hp - 4;
    const bool hvalid = (h >= 0 && h < 64);
    if (hvalid) {
        #pragma unroll
        for (int it = 0; it < 16; ++it) {
            int idx = it * 256 + tid;
            int cin = idx >> 6, w = idx & 63;           // w fastest -> coalesced
            lds[w * 65 + cin] = x[((b * 64 + cin) * 64 + h) * 64 + w];
        }
    }
    __syncthreads();
    #pragma unroll
    for (int it = 0; it < 18; ++it) {
        int o = it * 256 + tid;                         // 72*64 = 4608 elems
        int wp = o >> 6, cin = o & 63;                  // cin fastest -> coalesced
        int w = wp - 4;
        float val = (hvalid && w >= 0 && w < 64) ? lds[w * 65 + cin] : 0.0f;
        xp[((b * 72 + hp) * 72 + wp) * 64 + cin] = f2bf(val);
    }
}

// ---------------------------------------------------------------------------
// Kernel 2: Wfb[t][ch'][cin] bf16, ch' = cout*32 + g, g = part*16 + m.
// ---------------------------------------------------------------------------
__global__ __launch_bounds__(256) void wf_kernel(const float* __restrict__ Tr,
                                                 const float* __restrict__ Ti,
                                                 const float* __restrict__ wr,
                                                 const float* __restrict__ wi,
                                                 ushort_t* __restrict__ Wfb) {
    __shared__ float lds[64 * 65];
    const int g   = blockIdx.x;        // 0..31 = part*16 + m
    const int t   = blockIdx.y;        // 0..80
    const int part = g >> 4, m = g & 15;
    const int tid = threadIdx.x;
    #pragma unroll
    for (int it = 0; it < 16; ++it) {
        int cc = it * 256 + tid;       // cc = cin*64 + cout, consecutive -> coalesced
        float acc = 0.f;
        #pragma unroll
        for (int j = 0; j < 8; ++j) {
            float tr  = Tr[(m * 81 + t) * 8 + j];       // wave-uniform (scalar)
            float ti  = Ti[(m * 81 + t) * 8 + j];
            float wrv = wr[(m * 8 + j) * 4096 + cc];
            float wiv = wi[(m * 8 + j) * 4096 + cc];
            acc += (part == 0) ? (tr * wrv - ti * wiv) : (tr * wiv + ti * wrv);
        }
        lds[(cc & 63) * 65 + (cc >> 6)] = acc;          // lds[cout][cin], stride-65
    }
    __syncthreads();
    #pragma unroll
    for (int it = 0; it < 16; ++it) {
        int o = it * 256 + tid;        // o = cout*64 + cin
        int cout = o >> 6, cin = o & 63;
        Wfb[(t * 2048 + cout * 32 + g) * 64 + cin] = f2bf(lds[cout * 65 + cin]);
    }
}

// ---------------------------------------------------------------------------
// Kernel 3: implicit-GEMM conv + fused square/group-reduce/bias epilogue.
// LDS layout (both As/Bs): byte addr of (row, seg16) = row*128 + (seg^(row&7))*16
// ---------------------------------------------------------------------------
__global__ __launch_bounds__(256, 3) void conv_kernel(const ushort_t* __restrict__ xp,
                                                      const ushort_t* __restrict__ Wfb,
                                                      const float* __restrict__ bias,
                                                      float* __restrict__ out) {
    __shared__ ushort_t As[128 * 64];   // [pixel][cin] 16 KB, xor-swizzled
    __shared__ ushort_t Bs[128 * 64];   // [ch'][cin]   16 KB, xor-swizzled

    const int pt  = blockIdx.x;         // 0..1023 pixel tile (fast -> B slice L2-hot)
    const int ct  = blockIdx.y;         // 0..15 channel tile
    const int b   = pt >> 5;
    const int h0  = (pt & 31) * 2;      // rows h0, h0+1
    const int tid = threadIdx.x;
    const int wv  = tid >> 6;
    const int lane = tid & 63;
    const int wrow = wv >> 1, wcol = wv & 1;   // wave quadrant: pixels / channels
    const int quad = lane >> 4, lr = lane & 15;
    const int sx   = lr & 7;            // read-side swizzle key (row&7 == lr&7)

    // write-side swizzle: lane loads the global 16B segment that belongs at
    // its fixed LDS slot (base + lane*16). row&7 == lane>>3, storedseg == lane&7
    // -> global seg = (lane&7) ^ (lane>>3).
    const int lsw = ((lane & ~7) | ((lane ^ (lane >> 3)) & 7)) * 16;

    float4v acc[4][4];
    #pragma unroll
    for (int i = 0; i < 4; ++i)
        #pragma unroll
        for (int j = 0; j < 4; ++j) {
            float4v z = {0.f, 0.f, 0.f, 0.f};
            acc[i][j] = z;
        }

    const char* xpb = (const char*)xp;
    const char* wfb = (const char*)Wfb;
    const size_t bbase = (size_t)(ct * 128 * 64) * 2;   // + t*2048*64*2 per tap

    for (int dy = 0; dy < 9; ++dy) {
        for (int dx = 0; dx < 9; ++dx) {
            const int t = dy * 9 + dx;
            __syncthreads();   // previous iter's readers done before overwrite
            if (wv < 2) {
                // waves 0,1: A chunks (1 KB each: 8 pixels x 64 cin)
                #pragma unroll
                for (int k = 0; k < 8; ++k) {
                    const int c = wv * 8 + k;
                    const int r = c >> 3;                  // pixel row 0/1
                    const char* g = xpb
                        + (size_t)(((b * 72 + h0 + r + dy) * 72 + dx) * 64) * 2
                        + (size_t)(c & 7) * 1024 + (size_t)lsw;
                    __builtin_amdgcn_global_load_lds((gptr_t)g,
                        (sptr_t)((char*)As + c * 1024), 16, 0, 0);
                }
            } else {
                // waves 2,3: B chunks
                #pragma unroll
                for (int k = 0; k < 8; ++k) {
                    const int c2 = (wv - 2) * 8 + k;
                    const char* g = wfb + bbase
                        + (size_t)t * (2048 * 64 * 2)
                        + (size_t)c2 * 1024 + (size_t)lsw;
                    __builtin_amdgcn_global_load_lds((gptr_t)g,
                        (sptr_t)((char*)Bs + c2 * 1024), 16, 0, 0);
                }
            }
            __syncthreads();

            #pragma unroll
            for (int kk = 0; kk < 2; ++kk) {
                short8 a[4], bb[4];
                const int sa = ((kk * 4 + quad) ^ sx) * 8;   // swizzled seg -> ushort idx
                #pragma unroll
                for (int i = 0; i < 4; ++i)
                    a[i] = *(const short8*)&As[(wrow * 64 + i * 16 + lr) * 64 + sa];
                #pragma unroll
                for (int j = 0; j < 4; ++j)
                    bb[j] = *(const short8*)&Bs[(wcol * 64 + j * 16 + lr) * 64 + sa];
                #pragma unroll
                for (int i = 0; i < 4; ++i)
                    #pragma unroll
                    for (int j = 0; j < 4; ++j)
                        acc[i][j] = __builtin_amdgcn_mfma_f32_16x16x32_bf16(
                            a[i], bb[j], acc[i][j], 0, 0, 0);
            }
        }
    }

    // Epilogue: wave's 64 channels = 2 couts x 32 groups (ch' = cout*32+g).
    const int c0 = ct * 4 + wcol * 2;
    const float b0 = bias[c0], b1 = bias[c0 + 1];
    #pragma unroll
    for (int i = 0; i < 4; ++i) {
        #pragma unroll
        for (int reg = 0; reg < 4; ++reg) {
            float v0 = acc[i][0][reg] * acc[i][0][reg] + acc[i][1][reg] * acc[i][1][reg];
            float v1 = acc[i][2][reg] * acc[i][2][reg] + acc[i][3][reg] * acc[i][3][reg];
            #pragma unroll
            for (int off = 1; off <= 8; off <<= 1) {
                v0 += __shfl_xor(v0, off, 64);
                v1 += __shfl_xor(v1, off, 64);
            }
            if (lr == 0) {
                const int p = wrow * 64 + i * 16 + quad * 4 + reg;
                const int h = h0 + (p >> 6), w = p & 63;
                out[((b * 64 + c0    ) * 64 + h) * 64 + w] = v0 + b0;
                out[((b * 64 + c0 + 1) * 64 + h) * 64 + w] = v1 + b1;
            }
        }
    }
}

// ---------------------------------------------------------------------------
extern "C" void kernel_launch(void* const* d_in, const int* in_sizes, int n_in,
                              void* d_out, int out_size, void* d_ws, size_t ws_size,
                              hipStream_t stream) {
    const float* x    = (const float*)d_in[0];
    const float* Tr   = (const float*)d_in[1];
    const float* Ti   = (const float*)d_in[2];
    const float* wr   = (const float*)d_in[3];
    const float* wi   = (const float*)d_in[4];
    const float* bias = (const float*)d_in[5];
    float* out = (float*)d_out;

    // workspace: xp = 32*72*72*64 bf16 = 21,233,664 B ; Wfb = 81*2048*64 bf16
    ushort_t* xp  = (ushort_t*)d_ws;
    ushort_t* Wfb = (ushort_t*)((char*)d_ws + 21233664);

    pad_kernel<<<dim3(72, 32), 256, 0, stream>>>(x, xp);
    wf_kernel<<<dim3(32, 81), 256, 0, stream>>>(Tr, Ti, wr, wi, Wfb);
    conv_kernel<<<dim3(1024, 16), 256, 0, stream>>>(xp, Wfb, bias, out);
}

// Round 3
// 2672.808 us; speedup vs baseline: 1.1110x; 1.0057x over previous
//
#include <hip/hip_runtime.h>
#include <stdint.h>

// ---------------------------------------------------------------------------
// BesselConv2d on MI355X (gfx950)
//
// k1: pad+convert x (fp32 NCHW) -> xp bf16 NHWC, zero-padded to 72x72.
// k2: build Wfb[tap][ch'][cin] bf16, ch' = cout*32 + (part*16+m).
// k3: implicit-GEMM conv, 128x128 block tile, 4 waves (64x64 each as
//     2x2 of 32x32x16 bf16 MFMA), fused square/group-reduce/bias epilogue.
//
// R3 changes vs R2:
//  - 16x16x32 -> 32x32x16 MFMA (half the MFMA instrs, 2495 TF ceiling).
//  - A-row sliding: stage full 72-px padded rows once per dy (18 KB) and
//    slide the 64-px window by dx inside LDS -> 8x less A staging traffic.
//  - XOR 16B-seg swizzle keyed on (px&7) kept; A read key becomes (col+dx)&7.
// ---------------------------------------------------------------------------

typedef unsigned short ushort_t;
typedef __attribute__((ext_vector_type(8))) short short8;     // 8 bf16 = 4 VGPRs
typedef __attribute__((ext_vector_type(16))) float float16v;  // 32x32 acc

typedef const void __attribute__((address_space(1)))* gptr_t;
typedef void __attribute__((address_space(3)))* sptr_t;

__device__ __forceinline__ ushort_t f2bf(float f) {
    union { float f; uint32_t u; } v; v.f = f;
    uint32_t u = v.u;
    u += 0x7fffu + ((u >> 16) & 1u);   // round-to-nearest-even
    return (ushort_t)(u >> 16);
}

// ---------------------------------------------------------------------------
// Kernel 1: x[32][64][64][64] (NCHW fp32) -> xp[32][72][72][64] (NHWC bf16)
// ---------------------------------------------------------------------------
__global__ __launch_bounds__(256) void pad_kernel(const float* __restrict__ x,
                                                  ushort_t* __restrict__ xp) {
    __shared__ float lds[64 * 65];
    const int hp  = blockIdx.x;   // 0..71
    const int b   = blockIdx.y;   // 0..31
    const int tid = threadIdx.x;
    const int h   = hp - 4;
    const bool hvalid = (h >= 0 && h < 64);
    if (hvalid) {
        #pragma unroll
        for (int it = 0; it < 16; ++it) {
            int idx = it * 256 + tid;
            int cin = idx >> 6, w = idx & 63;
            lds[w * 65 + cin] = x[((b * 64 + cin) * 64 + h) * 64 + w];
        }
    }
    __syncthreads();
    #pragma unroll
    for (int it = 0; it < 18; ++it) {
        int o = it * 256 + tid;
        int wp = o >> 6, cin = o & 63;
        int w = wp - 4;
        float val = (hvalid && w >= 0 && w < 64) ? lds[w * 65 + cin] : 0.0f;
        xp[((b * 72 + hp) * 72 + wp) * 64 + cin] = f2bf(val);
    }
}

// ---------------------------------------------------------------------------
// Kernel 2: Wfb[t][ch'][cin] bf16, ch' = cout*32 + g, g = part*16 + m.
// ---------------------------------------------------------------------------
__global__ __launch_bounds__(256) void wf_kernel(const float* __restrict__ Tr,
                                                 const float* __restrict__ Ti,
                                                 const float* __restrict__ wr,
                                                 const float* __restrict__ wi,
                                                 ushort_t* __restrict__ Wfb) {
    __shared__ float lds[64 * 65];
    const int g   = blockIdx.x;        // 0..31
    const int t   = blockIdx.y;        // 0..80
    const int part = g >> 4, m = g & 15;
    const int tid = threadIdx.x;
    #pragma unroll
    for (int it = 0; it < 16; ++it) {
        int cc = it * 256 + tid;       // cin*64 + cout
        float acc = 0.f;
        #pragma unroll
        for (int j = 0; j < 8; ++j) {
            float tr  = Tr[(m * 81 + t) * 8 + j];
            float ti  = Ti[(m * 81 + t) * 8 + j];
            float wrv = wr[(m * 8 + j) * 4096 + cc];
            float wiv = wi[(m * 8 + j) * 4096 + cc];
            acc += (part == 0) ? (tr * wrv - ti * wiv) : (tr * wiv + ti * wrv);
        }
        lds[(cc & 63) * 65 + (cc >> 6)] = acc;
    }
    __syncthreads();
    #pragma unroll
    for (int it = 0; it < 16; ++it) {
        int o = it * 256 + tid;        // cout*64 + cin
        int cout = o >> 6, cin = o & 63;
        Wfb[(t * 2048 + cout * 32 + g) * 64 + cin] = f2bf(lds[cout * 65 + cin]);
    }
}

// ---------------------------------------------------------------------------
// Kernel 3: implicit-GEMM conv.
// As: 2 full padded rows [2][72][64] (swizzled); Bs: per-tap [128][64].
// Swizzle: 16B seg of row r stored at seg^(r&7)  (r = px for As, ch for Bs).
// ---------------------------------------------------------------------------
__global__ __launch_bounds__(256, 4) void conv_kernel(const ushort_t* __restrict__ xp,
                                                      const ushort_t* __restrict__ Wfb,
                                                      const float* __restrict__ bias,
                                                      float* __restrict__ out) {
    __shared__ alignas(16) ushort_t As[2 * 72 * 64];   // 18 KB
    __shared__ alignas(16) ushort_t Bs[128 * 64];      // 16 KB

    const int pt   = blockIdx.x;        // 0..1023 (fast -> same-ct blocks concurrent)
    const int ct   = blockIdx.y;        // 0..15
    const int b    = pt >> 5;
    const int h0   = (pt & 31) * 2;     // output rows h0, h0+1
    const int tid  = threadIdx.x;
    const int wv   = tid >> 6;
    const int lane = tid & 63;
    const int wrow = wv >> 1, wcol = wv & 1;
    const int c31  = lane & 31;         // MFMA m/n index
    const int kh   = lane >> 5;         // k-half
    // write-side swizzle for global_load_lds source lanes
    const int lsw  = ((lane & ~7) | ((lane ^ (lane >> 3)) & 7)) * 16;

    float16v acc[2][2];
    #pragma unroll
    for (int i = 0; i < 2; ++i)
        #pragma unroll
        for (int j = 0; j < 2; ++j)
            #pragma unroll
            for (int r = 0; r < 16; ++r) acc[i][j][r] = 0.f;

    const char* xpb = (const char*)xp;
    const char* wfb = (const char*)Wfb + (size_t)(ct * 128) * 128;  // ct row block

    for (int dy = 0; dy < 9; ++dy) {
        __syncthreads();   // readers of previous As/Bs done
        // stage A: rows h0+dy, h0+dy+1 (full 72 px, 9 KB each = 9 chunks)
        #pragma unroll
        for (int k2 = 0; k2 < 5; ++k2) {
            const int c = wv + 4 * k2;          // 18 chunks over 4 waves
            if (c < 18) {
                const int r  = (c >= 9) ? 1 : 0;
                const int cs = c - 9 * r;
                const char* g = xpb
                    + (size_t)((b * 72 + h0 + dy + r) * 72) * 128
                    + (size_t)cs * 1024 + (size_t)lsw;
                __builtin_amdgcn_global_load_lds((gptr_t)g,
                    (sptr_t)((char*)As + c * 1024), 16, 0, 0);
            }
        }
        for (int dx = 0; dx < 9; ++dx) {
            const int t = dy * 9 + dx;
            if (dx > 0) __syncthreads();        // prev Bs readers done
            // stage B tap tile: 16 chunks, 4 per wave
            #pragma unroll
            for (int k2 = 0; k2 < 4; ++k2) {
                const int c2 = wv * 4 + k2;
                const char* g = wfb + (size_t)t * (2048 * 128)
                    + (size_t)c2 * 1024 + (size_t)lsw;
                __builtin_amdgcn_global_load_lds((gptr_t)g,
                    (sptr_t)((char*)Bs + c2 * 1024), 16, 0, 0);
            }
            __syncthreads();                    // As (dx==0) + Bs ready

            const int akey = (c31 + dx) & 7;    // A swizzle key
            const int bkey = c31 & 7;           // B swizzle key
            const int apx  = wrow * 72 + c31 + dx;
            #pragma unroll
            for (int kk = 0; kk < 4; ++kk) {
                const int ka = kk * 2 + kh;
                short8 a0 = *(const short8*)&As[(apx     ) * 64 + ((ka ^ akey) * 8)];
                short8 a1 = *(const short8*)&As[(apx + 32) * 64 + ((ka ^ akey) * 8)];
                short8 b0 = *(const short8*)&Bs[(wcol * 64 + c31     ) * 64 + ((ka ^ bkey) * 8)];
                short8 b1 = *(const short8*)&Bs[(wcol * 64 + c31 + 32) * 64 + ((ka ^ bkey) * 8)];
                acc[0][0] = __builtin_amdgcn_mfma_f32_32x32x16_bf16(a0, b0, acc[0][0], 0, 0, 0);
                acc[0][1] = __builtin_amdgcn_mfma_f32_32x32x16_bf16(a0, b1, acc[0][1], 0, 0, 0);
                acc[1][0] = __builtin_amdgcn_mfma_f32_32x32x16_bf16(a1, b0, acc[1][0], 0, 0, 0);
                acc[1][1] = __builtin_amdgcn_mfma_f32_32x32x16_bf16(a1, b1, acc[1][1], 0, 0, 0);
            }
        }
    }

    // Epilogue. acc[i][j]: 32x32 block, col (=group g) = c31, cout = ct*4+wcol*2+j,
    // row = (r&3) + 8*(r>>2) + 4*kh, pixel w = i*32+row, h = h0+wrow.
    const int coutBase = ct * 4 + wcol * 2;
    const int h = h0 + wrow;
    #pragma unroll
    for (int j = 0; j < 2; ++j) {
        const float bj = bias[coutBase + j];
        #pragma unroll
        for (int i = 0; i < 2; ++i) {
            #pragma unroll
            for (int r = 0; r < 16; ++r) {
                float v = acc[i][j][r];
                v *= v;
                #pragma unroll
                for (int off = 1; off <= 16; off <<= 1)
                    v += __shfl_xor(v, off, 64);
                if (c31 == 0) {
                    const int row = (r & 3) + 8 * (r >> 2) + 4 * kh;
                    const int w = i * 32 + row;
                    out[((b * 64 + coutBase + j) * 64 + h) * 64 + w] = v + bj;
                }
            }
        }
    }
}

// ---------------------------------------------------------------------------
extern "C" void kernel_launch(void* const* d_in, const int* in_sizes, int n_in,
                              void* d_out, int out_size, void* d_ws, size_t ws_size,
                              hipStream_t stream) {
    const float* x    = (const float*)d_in[0];
    const float* Tr   = (const float*)d_in[1];
    const float* Ti   = (const float*)d_in[2];
    const float* wr   = (const float*)d_in[3];
    const float* wi   = (const float*)d_in[4];
    const float* bias = (const float*)d_in[5];
    float* out = (float*)d_out;

    ushort_t* xp  = (ushort_t*)d_ws;                          // 21,233,664 B
    ushort_t* Wfb = (ushort_t*)((char*)d_ws + 21233664);      // 21,233,664 B

    pad_kernel<<<dim3(72, 32), 256, 0, stream>>>(x, xp);
    wf_kernel<<<dim3(32, 81), 256, 0, stream>>>(Tr, Ti, wr, wi, Wfb);
    conv_kernel<<<dim3(1024, 16), 256, 0, stream>>>(xp, Wfb, bias, out);
}